// Round 10
// baseline (297.814 us; speedup 1.0000x reference)
//
#include <hip/hip_runtime.h>

#define N_NODES 100000
#define N_EDGES 1600000
#define BSHIFT 7
#define NBUCK 782     // ceil(N_NODES/128)
#define NCHUNK 500
#define CH 3200       // N_EDGES / NCHUNK exactly
#define SLAB 4096     // fixed per-bucket slab capacity (Poisson(2048): overflow ~ +45 sigma)
#define SLAB_SHIFT 12

typedef __attribute__((ext_vector_type(8))) short bf16x8;
typedef __attribute__((ext_vector_type(4))) float f32x4;

// bf16 helpers (RTNE pack; unpack = shift to high half)
__device__ __forceinline__ unsigned pack_bf16x2(float a, float b) {
  unsigned ua = __float_as_uint(a);
  unsigned ub = __float_as_uint(b);
  ua = ua + 0x7fffu + ((ua >> 16) & 1u);
  ub = ub + 0x7fffu + ((ub >> 16) & 1u);
  return (ua >> 16) | (ub & 0xffff0000u);
}
__device__ __forceinline__ unsigned short bf16u(float f) {
  unsigned u = __float_as_uint(f);
  u = u + 0x7fffu + ((u >> 16) & 1u);
  return (unsigned short)(u >> 16);
}
__device__ __forceinline__ float bf_lo(unsigned u) { return __uint_as_float(u << 16); }
__device__ __forceinline__ float bf_hi(unsigned u) { return __uint_as_float(u & 0xffff0000u); }

// ---- k_part: single-pass partition into fixed slabs (replaces hist/offs/bscan/part) -----
// Per chunk: stage 3200 edges in LDS, LDS-hist both streams, reserve slab ranges with ONE
// global atomicAdd per (block,bucket), LDS-sort, write both streams as coalesced runs.
// Also does the one-time weight transpose/pack (blocks 0..63).

__global__ __launch_bounds__(256) void k_part(const int* __restrict__ src,
                                              const int* __restrict__ dst,
                                              unsigned* __restrict__ gcurD,
                                              unsigned* __restrict__ gcurS,
                                              int* __restrict__ ebufD,
                                              unsigned char* __restrict__ ebufS,
                                              const float* __restrict__ W1,
                                              const float* __restrict__ W2,
                                              unsigned short* __restrict__ Wt1,
                                              unsigned short* __restrict__ Wt2) {
  __shared__ int pk_s[CH];
  __shared__ unsigned short bkD[CH];
  __shared__ unsigned short bkS[CH];
  __shared__ unsigned char rsS[CH];
  __shared__ int srt[CH];
  __shared__ int sad[CH];
  __shared__ unsigned cnt[NBUCK];
  __shared__ int gb[NBUCK];
  __shared__ unsigned pscan[256];
  const int t = threadIdx.x, j = blockIdx.x;
  if (j < 64) {  // fused weight prep (once)
    int q = j * 256 + t;
    {
      int n = q >> 7, k = q & 127;
      Wt1[n * 128 + k] = bf16u(W1[k * 128 + n]);
    }
    if (q < 48 * 128) {
      int n = q >> 7, k = q & 127;
      float v = (n < 40) ? W2[k * 40 + n] : 0.f;
      Wt2[n * 128 + k] = bf16u(v);
    }
  }
  const int e0 = j * CH;
  for (int i = t; i < CH; i += 256) {
    int d = dst[e0 + i], s = src[e0 + i];
    pk_s[i] = ((d & 127) << 17) | s;
    bkD[i] = (unsigned short)((unsigned)d >> BSHIFT);
    bkS[i] = (unsigned short)((unsigned)s >> BSHIFT);
    rsS[i] = (unsigned char)(s & 127);
  }
  // ---- pass 1: dst stream ----
  for (int i = t; i < NBUCK; i += 256) cnt[i] = 0u;
  __syncthreads();
  for (int i = t; i < CH; i += 256) atomicAdd(&cnt[bkD[i]], 1u);
  __syncthreads();
  unsigned loc[4], ssum = 0;
#pragma unroll
  for (int i = 0; i < 4; ++i) {
    int idx = t * 4 + i;
    loc[i] = (idx < NBUCK) ? cnt[idx] : 0u;
    ssum += loc[i];
  }
  pscan[t] = ssum;
  __syncthreads();
  for (int d2 = 1; d2 < 256; d2 <<= 1) {
    unsigned a = (t >= d2) ? pscan[t - d2] : 0u;
    __syncthreads();
    pscan[t] += a;
    __syncthreads();
  }
  unsigned run = pscan[t] - ssum;
#pragma unroll
  for (int i = 0; i < 4; ++i) {
    int idx = t * 4 + i;
    if (idx < NBUCK) {
      unsigned c = loc[i];
      unsigned gbase = c ? atomicAdd(&gcurD[idx], c) : 0u;
      gb[idx] = (idx << SLAB_SHIFT) + (int)gbase - (int)run;  // sad = gb[b] + p
      cnt[idx] = run;  // local cursor
      run += c;
    }
  }
  __syncthreads();
  for (int i = t; i < CH; i += 256) {
    int b = bkD[i];
    unsigned pos = atomicAdd(&cnt[b], 1u);
    srt[pos] = pk_s[i];
    sad[pos] = gb[b] + (int)pos;
  }
  __syncthreads();
  for (int i = t; i < CH; i += 256) {
    unsigned a = (unsigned)sad[i];
    if (a < (unsigned)(NBUCK * SLAB)) ebufD[a] = srt[i];
  }
  __syncthreads();
  // ---- pass 2: src stream (residue bytes) ----
  for (int i = t; i < NBUCK; i += 256) cnt[i] = 0u;
  __syncthreads();
  for (int i = t; i < CH; i += 256) atomicAdd(&cnt[bkS[i]], 1u);
  __syncthreads();
  ssum = 0;
#pragma unroll
  for (int i = 0; i < 4; ++i) {
    int idx = t * 4 + i;
    loc[i] = (idx < NBUCK) ? cnt[idx] : 0u;
    ssum += loc[i];
  }
  pscan[t] = ssum;
  __syncthreads();
  for (int d2 = 1; d2 < 256; d2 <<= 1) {
    unsigned a = (t >= d2) ? pscan[t - d2] : 0u;
    __syncthreads();
    pscan[t] += a;
    __syncthreads();
  }
  run = pscan[t] - ssum;
#pragma unroll
  for (int i = 0; i < 4; ++i) {
    int idx = t * 4 + i;
    if (idx < NBUCK) {
      unsigned c = loc[i];
      unsigned gbase = c ? atomicAdd(&gcurS[idx], c) : 0u;
      gb[idx] = (idx << SLAB_SHIFT) + (int)gbase - (int)run;
      cnt[idx] = run;
      run += c;
    }
  }
  __syncthreads();
  unsigned char* srtB = (unsigned char*)srt;
  for (int i = t; i < CH; i += 256) {
    int b = bkS[i];
    unsigned pos = atomicAdd(&cnt[b], 1u);
    srtB[pos] = rsS[i];
    sad[pos] = gb[b] + (int)pos;
  }
  __syncthreads();
  for (int i = t; i < CH; i += 256) {
    unsigned a = (unsigned)sad[i];
    if (a < (unsigned)(NBUCK * SLAB)) ebufS[a] = srtB[i];
  }
}

// ---- k_buckets: per-bucket: degrees -> oi/ii/coi, row_ptr/deg, clustered csr fill -------
// Reads slab segment [b*SLAB, b*SLAB + gcur[b]); csr_src written slab-based.

__global__ __launch_bounds__(256) void k_buckets(const int* __restrict__ ebufD,
                                                 const unsigned char* __restrict__ ebufS,
                                                 const unsigned* __restrict__ gcurD,
                                                 const unsigned* __restrict__ gcurS,
                                                 float* __restrict__ oi,
                                                 int* __restrict__ row_ptr,
                                                 int* __restrict__ deg,
                                                 int* __restrict__ csr_src,
                                                 float* __restrict__ ii,
                                                 float* __restrict__ coi) {
  __shared__ unsigned cntS[128];
  __shared__ unsigned cntD[128];
  __shared__ unsigned sc2[128];
  __shared__ int eL[3072];
  const int b = blockIdx.x, t = threadIdx.x;
  const int node0 = b << BSHIFT;
  const int base = b << SLAB_SHIFT;
  int cd = (int)gcurD[b]; if (cd > SLAB) cd = SLAB;
  int cs = (int)gcurS[b]; if (cs > SLAB) cs = SLAB;
  if (t < 128) { cntS[t] = 0u; cntD[t] = 0u; }
  __syncthreads();
  for (int j = t; j < cs; j += 256)
    atomicAdd(&cntS[ebufS[base + j]], 1u);
  const bool fit = (cd <= 3072);
  for (int j = t; j < cd; j += 256) {
    int pk = ebufD[base + j];
    if (fit) eL[j] = pk;
    atomicAdd(&cntD[(unsigned)pk >> 17], 1u);
  }
  __syncthreads();
  unsigned cD = (t < 128) ? cntD[t] : 0u;
  if (t < 128) sc2[t] = cD;
  __syncthreads();
  for (int d = 1; d < 128; d <<= 1) {
    unsigned a = (t < 128 && t >= d) ? sc2[t - d] : 0u;
    __syncthreads();
    if (t < 128) sc2[t] += a;
    __syncthreads();
  }
  if (t < 128) {
    unsigned ex = sc2[t] - cD;  // exclusive prefix
    int n = node0 + t;
    if (n < N_NODES) {
      unsigned csn = cntS[t]; if (csn < 1u) csn = 1u;
      float o = rsqrtf((float)csn);
      oi[n] = o;
      row_ptr[n] = base + (int)ex;
      deg[n] = (int)cD;
      unsigned c = cD; if (c < 1u) c = 1u;
      float iv = rsqrtf((float)c);
      ii[n] = iv;
      coi[n] = iv * o;  // relu(ii*agg)*oi == (ii*oi)*relu(agg)
    }
    cntD[t] = ex;  // reuse as cursors
  }
  __syncthreads();
  for (int j = t; j < cd; j += 256) {
    int pk = fit ? eL[j] : ebufD[base + j];
    unsigned dn = (unsigned)pk >> 17;
    unsigned slot = atomicAdd(&cntD[dn], 1u);
    csr_src[base + (int)slot] = pk & 0x1FFFF;
  }
}

// ---------------- GEMM1 (MFMA bf16): h1b = bf16((x*oi) @ W1), 100k x 128 x 128 ----------------

#define LPAD 136

__global__ __launch_bounds__(256) void k_gemm1(const float* __restrict__ x,
                                               const float* __restrict__ oi,
                                               const unsigned short* __restrict__ Wt1,
                                               unsigned short* __restrict__ h1b) {
  __shared__ unsigned short Xs[64 * LPAD];
  __shared__ unsigned short Ws[128 * LPAD];
  const int t = threadIdx.x;
  const int row0 = blockIdx.x * 64;
#pragma unroll
  for (int j = 0; j < 8; ++j) {
    int q = t + 256 * j;
    int n = q >> 4, c = q & 15;
    *(uint4*)(Ws + n * LPAD + c * 8) = *(const uint4*)(Wt1 + n * 128 + c * 8);
  }
#pragma unroll
  for (int j = 0; j < 4; ++j) {
    int q = t + 256 * j;
    int r = q >> 4, c = q & 15;
    int gr = row0 + r; if (gr >= N_NODES) gr = N_NODES - 1;
    const float* xp = x + (size_t)gr * 128 + c * 8;
    float4 v0 = *(const float4*)(xp);
    float4 v1 = *(const float4*)(xp + 4);
    float s = oi[gr];
    uint4 pk;
    pk.x = pack_bf16x2(v0.x * s, v0.y * s);
    pk.y = pack_bf16x2(v0.z * s, v0.w * s);
    pk.z = pack_bf16x2(v1.x * s, v1.y * s);
    pk.w = pack_bf16x2(v1.z * s, v1.w * s);
    *(uint4*)(Xs + r * LPAD + c * 8) = pk;
  }
  __syncthreads();
  const int w = t >> 6, lane = t & 63;
  const int m = lane & 15;
  const int q8 = (lane >> 4) * 8;
  f32x4 acc[8];
#pragma unroll
  for (int i = 0; i < 8; ++i) acc[i] = (f32x4){0.f, 0.f, 0.f, 0.f};
  const unsigned short* xrow = Xs + (w * 16 + m) * LPAD;
#pragma unroll
  for (int ks = 0; ks < 4; ++ks) {
    bf16x8 a = *(const bf16x8*)(xrow + ks * 32 + q8);
#pragma unroll
    for (int ct = 0; ct < 8; ++ct) {
      bf16x8 b = *(const bf16x8*)(Ws + (ct * 16 + m) * LPAD + ks * 32 + q8);
      acc[ct] = __builtin_amdgcn_mfma_f32_16x16x32_bf16(a, b, acc[ct], 0, 0, 0);
    }
  }
  const int rbase = row0 + w * 16 + (lane >> 4) * 4;
#pragma unroll
  for (int ct = 0; ct < 8; ++ct) {
    int coln = ct * 16 + m;
#pragma unroll
    for (int r = 0; r < 4; ++r) {
      int grow = rbase + r;
      if (grow < N_NODES) h1b[(size_t)grow * 128 + coln] = bf16u(acc[ct][r]);
    }
  }
}

// ---------------- AGG1+GEMM2 fused: h2b = bf16( (coi*relu(sum h1[src])) @ W2 ) -----------

__global__ __launch_bounds__(256) void k_agg1g2(const unsigned short* __restrict__ h1b,
                                                const int* __restrict__ csr_src,
                                                const int* __restrict__ row_ptr,
                                                const int* __restrict__ deg,
                                                const float* __restrict__ coi,
                                                const unsigned short* __restrict__ Wt2,
                                                unsigned short* __restrict__ h2b) {
  __shared__ unsigned short Gs[16 * LPAD];
  __shared__ unsigned short Ws[48 * LPAD];
  const int t = threadIdx.x;
  const int node0 = blockIdx.x * 16;
#pragma unroll
  for (int j = 0; j < 3; ++j) {  // W2^T 48x128 -> LDS (L2-hot)
    int q = t + 256 * j;
    int n = q >> 4, cc = q & 15;
    *(uint4*)(Ws + n * LPAD + cc * 8) = *(const uint4*)(Wt2 + n * 128 + cc * 8);
  }
  const int node = node0 + (t >> 4);
  const int c = t & 15;
  const int beg = row_ptr[node];
  const int end = beg + deg[node];
  float4 a0 = make_float4(0.f, 0.f, 0.f, 0.f);
  float4 a1 = make_float4(0.f, 0.f, 0.f, 0.f);
  int j = beg;
  for (; j + 8 <= end; j += 8) {
    uint4 v[8];
#pragma unroll
    for (int i = 0; i < 8; ++i) {
      int s = csr_src[j + i];
      v[i] = *(const uint4*)(h1b + (size_t)s * 128 + 8 * c);
    }
#pragma unroll
    for (int i = 0; i < 8; ++i) {
      a0.x += bf_lo(v[i].x); a0.y += bf_hi(v[i].x);
      a0.z += bf_lo(v[i].y); a0.w += bf_hi(v[i].y);
      a1.x += bf_lo(v[i].z); a1.y += bf_hi(v[i].z);
      a1.z += bf_lo(v[i].w); a1.w += bf_hi(v[i].w);
    }
  }
  if (j + 4 <= end) {
    uint4 v[4];
#pragma unroll
    for (int i = 0; i < 4; ++i) {
      int s = csr_src[j + i];
      v[i] = *(const uint4*)(h1b + (size_t)s * 128 + 8 * c);
    }
#pragma unroll
    for (int i = 0; i < 4; ++i) {
      a0.x += bf_lo(v[i].x); a0.y += bf_hi(v[i].x);
      a0.z += bf_lo(v[i].y); a0.w += bf_hi(v[i].y);
      a1.x += bf_lo(v[i].z); a1.y += bf_hi(v[i].z);
      a1.z += bf_lo(v[i].w); a1.w += bf_hi(v[i].w);
    }
    j += 4;
  }
  for (; j < end; ++j) {
    int s = csr_src[j];
    uint4 v = *(const uint4*)(h1b + (size_t)s * 128 + 8 * c);
    a0.x += bf_lo(v.x); a0.y += bf_hi(v.x); a0.z += bf_lo(v.y); a0.w += bf_hi(v.y);
    a1.x += bf_lo(v.z); a1.y += bf_hi(v.z); a1.z += bf_lo(v.w); a1.w += bf_hi(v.w);
  }
  float sc = coi[node];
  uint4 pk;
  pk.x = pack_bf16x2(fmaxf(a0.x, 0.f) * sc, fmaxf(a0.y, 0.f) * sc);
  pk.y = pack_bf16x2(fmaxf(a0.z, 0.f) * sc, fmaxf(a0.w, 0.f) * sc);
  pk.z = pack_bf16x2(fmaxf(a1.x, 0.f) * sc, fmaxf(a1.y, 0.f) * sc);
  pk.w = pack_bf16x2(fmaxf(a1.z, 0.f) * sc, fmaxf(a1.w, 0.f) * sc);
  *(uint4*)(Gs + (t >> 4) * LPAD + 8 * c) = pk;
  __syncthreads();
  // GEMM2: 16x128 @ (48x128)^T -> 16x48 ; wave w = col-tile w (0..2), wave 3 idle
  const int w = t >> 6, lane = t & 63;
  if (w < 3) {
    const int m = lane & 15;
    const int q8 = (lane >> 4) * 8;
    f32x4 acc = (f32x4){0.f, 0.f, 0.f, 0.f};
    const unsigned short* grow_p = Gs + m * LPAD;
#pragma unroll
    for (int ks = 0; ks < 4; ++ks) {
      bf16x8 a = *(const bf16x8*)(grow_p + ks * 32 + q8);
      bf16x8 b = *(const bf16x8*)(Ws + (w * 16 + m) * LPAD + ks * 32 + q8);
      acc = __builtin_amdgcn_mfma_f32_16x16x32_bf16(a, b, acc, 0, 0, 0);
    }
    int coln = w * 16 + m;
    if (coln < 40) {
      const int rbase = (lane >> 4) * 4;
#pragma unroll
      for (int r = 0; r < 4; ++r)
        h2b[(size_t)(node0 + rbase + r) * 64 + coln] = bf16u(acc[r]);
    }
  }
}

// ---------------- AGG2: out = ii * sum h2[src]  (8 lanes/node, uint4; lanes 0-4 active) ----

__global__ __launch_bounds__(256) void k_agg2(const unsigned short* __restrict__ h2b,
                                              const int* __restrict__ csr_src,
                                              const int* __restrict__ row_ptr,
                                              const int* __restrict__ deg,
                                              const float* __restrict__ ii,
                                              float* __restrict__ out) {
  const int t = threadIdx.x;
  const int node = blockIdx.x * 32 + (t >> 3);
  const int c = t & 7;
  if (c >= 5) return;  // 40 ch = 5 lanes x 8 ch
  const int beg = row_ptr[node];
  const int end = beg + deg[node];
  float a0 = 0.f, a1 = 0.f, a2 = 0.f, a3 = 0.f, a4 = 0.f, a5 = 0.f, a6 = 0.f, a7 = 0.f;
  int j = beg;
  for (; j + 8 <= end; j += 8) {
    uint4 v[8];
#pragma unroll
    for (int i = 0; i < 8; ++i) {
      int s = csr_src[j + i];
      v[i] = *(const uint4*)(h2b + (size_t)s * 64 + 8 * c);
    }
#pragma unroll
    for (int i = 0; i < 8; ++i) {
      a0 += bf_lo(v[i].x); a1 += bf_hi(v[i].x);
      a2 += bf_lo(v[i].y); a3 += bf_hi(v[i].y);
      a4 += bf_lo(v[i].z); a5 += bf_hi(v[i].z);
      a6 += bf_lo(v[i].w); a7 += bf_hi(v[i].w);
    }
  }
  if (j + 4 <= end) {
    uint4 v[4];
#pragma unroll
    for (int i = 0; i < 4; ++i) {
      int s = csr_src[j + i];
      v[i] = *(const uint4*)(h2b + (size_t)s * 64 + 8 * c);
    }
#pragma unroll
    for (int i = 0; i < 4; ++i) {
      a0 += bf_lo(v[i].x); a1 += bf_hi(v[i].x);
      a2 += bf_lo(v[i].y); a3 += bf_hi(v[i].y);
      a4 += bf_lo(v[i].z); a5 += bf_hi(v[i].z);
      a6 += bf_lo(v[i].w); a7 += bf_hi(v[i].w);
    }
    j += 4;
  }
  for (; j < end; ++j) {
    int s = csr_src[j];
    uint4 v = *(const uint4*)(h2b + (size_t)s * 64 + 8 * c);
    a0 += bf_lo(v.x); a1 += bf_hi(v.x);
    a2 += bf_lo(v.y); a3 += bf_hi(v.y);
    a4 += bf_lo(v.z); a5 += bf_hi(v.z);
    a6 += bf_lo(v.w); a7 += bf_hi(v.w);
  }
  float sc = ii[node];
  float4 o0 = make_float4(a0 * sc, a1 * sc, a2 * sc, a3 * sc);
  float4 o1 = make_float4(a4 * sc, a5 * sc, a6 * sc, a7 * sc);
  float* op = out + (size_t)node * 40 + 8 * c;
  *(float4*)(op) = o0;
  *(float4*)(op + 4) = o1;
}

// ---------------- launch ----------------

extern "C" void kernel_launch(void* const* d_in, const int* in_sizes, int n_in,
                              void* d_out, int out_size, void* d_ws, size_t ws_size,
                              hipStream_t stream) {
  const float* x  = (const float*)d_in[0];
  const int* ei   = (const int*)d_in[1];
  const float* W1 = (const float*)d_in[2];
  const float* W2 = (const float*)d_in[3];
  const int* src = ei;
  const int* dst = ei + N_EDGES;
  float* out = (float*)d_out;

  char* p = (char*)d_ws;
  auto alloc = [&](size_t b) -> void* {
    char* r = p;
    p += (b + 255) & ~(size_t)255;
    return (void*)r;
  };
  float* oi             = (float*)alloc((size_t)N_NODES * 4);
  float* ii             = (float*)alloc((size_t)N_NODES * 4);
  float* coi            = (float*)alloc((size_t)N_NODES * 4);
  int* row_ptr          = (int*)alloc((size_t)N_NODES * 4);
  int* deg              = (int*)alloc((size_t)N_NODES * 4);
  unsigned* gcur        = (unsigned*)alloc((size_t)2 * NBUCK * 4);
  int* ebufD            = (int*)alloc((size_t)NBUCK * SLAB * 4);
  unsigned char* ebufS  = (unsigned char*)alloc((size_t)NBUCK * SLAB);
  int* csr_src          = (int*)alloc((size_t)NBUCK * SLAB * 4);
  unsigned short* Wt1   = (unsigned short*)alloc((size_t)128 * 128 * 2);
  unsigned short* Wt2   = (unsigned short*)alloc((size_t)48 * 128 * 2);
  unsigned short* h1b   = (unsigned short*)alloc((size_t)N_NODES * 128 * 2);
  unsigned short* h2b   = (unsigned short*)alloc((size_t)N_NODES * 64 * 2);
  unsigned* gcurD = gcur;
  unsigned* gcurS = gcur + NBUCK;

  hipMemsetAsync(gcur, 0, (size_t)2 * NBUCK * 4, stream);
  k_part<<<NCHUNK, 256, 0, stream>>>(src, dst, gcurD, gcurS, ebufD, ebufS,
                                     W1, W2, Wt1, Wt2);
  k_buckets<<<NBUCK, 256, 0, stream>>>(ebufD, ebufS, gcurD, gcurS, oi, row_ptr, deg,
                                       csr_src, ii, coi);
  k_gemm1<<<(N_NODES + 63) / 64, 256, 0, stream>>>(x, oi, Wt1, h1b);
  k_agg1g2<<<N_NODES / 16, 256, 0, stream>>>(h1b, csr_src, row_ptr, deg, coi, Wt2, h2b);
  k_agg2<<<N_NODES / 32, 256, 0, stream>>>(h2b, csr_src, row_ptr, deg, ii, out);
}

// Round 11
// 251.119 us; speedup vs baseline: 1.1859x; 1.1859x over previous
//
#include <hip/hip_runtime.h>

#define N_NODES 100000
#define N_EDGES 1600000
#define BSHIFT 7
#define NBUCK 782     // ceil(N_NODES/128)
#define NB2 (2 * NBUCK)
#define NCHUNK 500
#define CH 3200       // N_EDGES / NCHUNK exactly

typedef __attribute__((ext_vector_type(8))) short bf16x8;
typedef __attribute__((ext_vector_type(4))) float f32x4;

// bf16 helpers (RTNE pack; unpack = shift to high half)
__device__ __forceinline__ unsigned pack_bf16x2(float a, float b) {
  unsigned ua = __float_as_uint(a);
  unsigned ub = __float_as_uint(b);
  ua = ua + 0x7fffu + ((ua >> 16) & 1u);
  ub = ub + 0x7fffu + ((ub >> 16) & 1u);
  return (ua >> 16) | (ub & 0xffff0000u);
}
__device__ __forceinline__ unsigned short bf16u(float f) {
  unsigned u = __float_as_uint(f);
  u = u + 0x7fffu + ((u >> 16) & 1u);
  return (unsigned short)(u >> 16);
}
__device__ __forceinline__ float bf_lo(unsigned u) { return __uint_as_float(u << 16); }
__device__ __forceinline__ float bf_hi(unsigned u) { return __uint_as_float(u & 0xffff0000u); }

// ---------------- counting-sort partition (histG [bucket][chunk]; fused weight prep) -------

__global__ __launch_bounds__(256) void k_hist(const int* __restrict__ src,
                                              const int* __restrict__ dst,
                                              unsigned* __restrict__ histGd,
                                              unsigned* __restrict__ histGs,
                                              const float* __restrict__ W1,
                                              const float* __restrict__ W2,
                                              unsigned short* __restrict__ Wt1,
                                              unsigned short* __restrict__ Wt2) {
  __shared__ unsigned hd[NBUCK];
  __shared__ unsigned hs[NBUCK];
  const int t = threadIdx.x, j = blockIdx.x;
  if (j < 64) {  // fused weight prep (once)
    int q = j * 256 + t;
    {
      int n = q >> 7, k = q & 127;
      Wt1[n * 128 + k] = bf16u(W1[k * 128 + n]);
    }
    if (q < 48 * 128) {
      int n = q >> 7, k = q & 127;
      float v = (n < 40) ? W2[k * 40 + n] : 0.f;
      Wt2[n * 128 + k] = bf16u(v);
    }
  }
  for (int i = t; i < NBUCK; i += 256) { hd[i] = 0u; hs[i] = 0u; }
  __syncthreads();
  const int e0 = j * CH;
  for (int e = e0 + t; e < e0 + CH; e += 256) {
    atomicAdd(&hd[(unsigned)dst[e] >> BSHIFT], 1u);
    atomicAdd(&hs[(unsigned)src[e] >> BSHIFT], 1u);
  }
  __syncthreads();
  for (int i = t; i < NBUCK; i += 256) {
    histGd[(size_t)i * NCHUNK + j] = hd[i];
    histGs[(size_t)i * NCHUNK + j] = hs[i];
  }
}

// block per (bucket, stream): exclusive scan of NCHUNK chunk-counts in place + total.
__global__ __launch_bounds__(256) void k_offs(unsigned* __restrict__ histGd,
                                              unsigned* __restrict__ histGs,
                                              unsigned* __restrict__ btot) {
  __shared__ unsigned sd[256];
  const int bu = blockIdx.x, t = threadIdx.x;
  unsigned* col = (bu < NBUCK) ? histGd + (size_t)bu * NCHUNK
                               : histGs + (size_t)(bu - NBUCK) * NCHUNK;
  unsigned v[2], s = 0;
#pragma unroll
  for (int i = 0; i < 2; ++i) {
    int idx = t * 2 + i;
    v[i] = (idx < NCHUNK) ? col[idx] : 0u;
    s += v[i];
  }
  sd[t] = s;
  __syncthreads();
  for (int d = 1; d < 256; d <<= 1) {
    unsigned a = (t >= d) ? sd[t - d] : 0u;
    __syncthreads();
    sd[t] += a;
    __syncthreads();
  }
  unsigned run = sd[t] - s;
#pragma unroll
  for (int i = 0; i < 2; ++i) {
    int idx = t * 2 + i;
    if (idx < NCHUNK) { unsigned tv = v[i]; col[idx] = run; run += tv; }
  }
  if (t == 255) btot[bu] = run;
}

// two blocks: scan dst totals -> bbase, src totals -> sbase.
__global__ __launch_bounds__(1024) void k_bscan2(const unsigned* __restrict__ btot,
                                                 int* __restrict__ bbase,
                                                 int* __restrict__ sbase,
                                                 int* __restrict__ row_ptr) {
  __shared__ unsigned sd[1024];
  const int t = threadIdx.x;
  const unsigned* bt = btot + (blockIdx.x ? NBUCK : 0);
  int* ob = blockIdx.x ? sbase : bbase;
  unsigned v = (t < NBUCK) ? bt[t] : 0u;
  sd[t] = v;
  __syncthreads();
  for (int d = 1; d < 1024; d <<= 1) {
    unsigned a = (t >= d) ? sd[t - d] : 0u;
    __syncthreads();
    sd[t] += a;
    __syncthreads();
  }
  if (t < NBUCK) ob[t] = (int)(sd[t] - v);
  if (t == 0) {
    ob[NBUCK] = N_EDGES;
    if (blockIdx.x == 0) row_ptr[N_NODES] = N_EDGES;
  }
}

// ---- k_part: LDS counting sort per chunk, both streams, ONE combined scan ---------------
// 51.9KB LDS (3 blocks/CU); ~22 barriers (was ~40). Write-out as sorted coalesced runs.

__global__ __launch_bounds__(256) void k_part(const int* __restrict__ src,
                                              const int* __restrict__ dst,
                                              const unsigned* __restrict__ histGd,
                                              const unsigned* __restrict__ histGs,
                                              const int* __restrict__ bbase,
                                              const int* __restrict__ sbase,
                                              int* __restrict__ ebuf,
                                              unsigned char* __restrict__ ebuf2) {
  __shared__ int pk_s[CH];
  __shared__ unsigned short bkD[CH];
  __shared__ int srt[CH];
  __shared__ unsigned short bkO[CH];
  __shared__ unsigned cnt[NB2];
  __shared__ int gb[NB2];
  __shared__ unsigned pscan[256];
  const int t = threadIdx.x, j = blockIdx.x;
  const int e0 = j * CH;
  for (int i = t; i < NB2; i += 256) cnt[i] = 0u;
  __syncthreads();
  for (int i = t; i < CH; i += 256) {
    int d = dst[e0 + i], s = src[e0 + i];
    pk_s[i] = ((d & 127) << 17) | s;
    int bd = (unsigned)d >> BSHIFT;
    bkD[i] = (unsigned short)bd;
    atomicAdd(&cnt[bd], 1u);
    atomicAdd(&cnt[NBUCK + ((unsigned)s >> BSHIFT)], 1u);
  }
  __syncthreads();
  // combined exclusive scan over cnt[0..NB2): dst positions [0,CH), src [CH,2CH)
  unsigned loc[7], ssum = 0;
#pragma unroll
  for (int k = 0; k < 7; ++k) {
    int idx = t * 7 + k;
    loc[k] = (idx < NB2) ? cnt[idx] : 0u;
    ssum += loc[k];
  }
  pscan[t] = ssum;
  __syncthreads();
  for (int d2 = 1; d2 < 256; d2 <<= 1) {
    unsigned a = (t >= d2) ? pscan[t - d2] : 0u;
    __syncthreads();
    pscan[t] += a;
    __syncthreads();
  }
  unsigned run = pscan[t] - ssum;
#pragma unroll
  for (int k = 0; k < 7; ++k) {
    int idx = t * 7 + k;
    if (idx < NBUCK) {
      cnt[idx] = run;
      gb[idx] = bbase[idx] + (int)histGd[(size_t)idx * NCHUNK + j] - (int)run;
    } else if (idx < NB2) {
      unsigned runS = run - CH;  // src section starts after CH dst entries
      cnt[idx] = runS;
      int b = idx - NBUCK;
      gb[idx] = sbase[b] + (int)histGs[(size_t)b * NCHUNK + j] - (int)runS;
    }
    run += loc[k];
  }
  __syncthreads();
  // scatter + write dst stream (packed ints)
  for (int i = t; i < CH; i += 256) {
    int b = bkD[i];
    unsigned pos = atomicAdd(&cnt[b], 1u);
    srt[pos] = pk_s[i];
    bkO[pos] = (unsigned short)b;
  }
  __syncthreads();
  for (int i = t; i < CH; i += 256)
    ebuf[gb[bkO[i]] + i] = srt[i];
  __syncthreads();
  // scatter + write src stream (residue bytes); srtB aliases srt
  unsigned char* srtB = (unsigned char*)srt;
  for (int i = t; i < CH; i += 256) {
    int s = pk_s[i] & 0x1FFFF;
    int b2 = NBUCK + ((unsigned)s >> BSHIFT);
    unsigned pos = atomicAdd(&cnt[b2], 1u);
    srtB[pos] = (unsigned char)(s & 127);
    bkO[pos] = (unsigned short)b2;
  }
  __syncthreads();
  for (int i = t; i < CH; i += 256)
    ebuf2[gb[bkO[i]] + i] = srtB[i];
}

// Fused per-bucket pass: (A) src-degree -> oi (kept in LDS for coi);
// (B) dst counts -> row_ptr/ii/coi (parallel 128-scan); (C) clustered csr_src fill.
// ebuf slice cached in LDS (<=3072 edges; Poisson(2048) -> overflow ~impossible; fallback).
__global__ __launch_bounds__(256) void k_buckets(const int* __restrict__ ebuf,
                                                 const unsigned char* __restrict__ ebuf2,
                                                 const int* __restrict__ bbase,
                                                 const int* __restrict__ sbase,
                                                 float* __restrict__ oi,
                                                 int* __restrict__ row_ptr,
                                                 int* __restrict__ csr_src,
                                                 float* __restrict__ ii,
                                                 float* __restrict__ coi) {
  __shared__ unsigned cntS[128];
  __shared__ unsigned cntD[128];
  __shared__ unsigned sc2[128];
  __shared__ int eL[3072];
  const int b = blockIdx.x, t = threadIdx.x;
  const int node0 = b << BSHIFT;
  if (t < 128) { cntS[t] = 0u; cntD[t] = 0u; }
  __syncthreads();
  const int sbeg = sbase[b], send = sbase[b + 1];
  for (int j = sbeg + t; j < send; j += 256)
    atomicAdd(&cntS[ebuf2[j]], 1u);
  const int base = bbase[b], end = bbase[b + 1];
  const int cnt = end - base;
  const bool fit = (cnt <= 3072);
  for (int j = t; j < cnt; j += 256) {
    int pk = ebuf[base + j];
    if (fit) eL[j] = pk;
    atomicAdd(&cntD[(unsigned)pk >> 17], 1u);
  }
  __syncthreads();
  unsigned cD = (t < 128) ? cntD[t] : 0u;
  if (t < 128) sc2[t] = cD;
  __syncthreads();
  for (int d = 1; d < 128; d <<= 1) {
    unsigned a = (t < 128 && t >= d) ? sc2[t - d] : 0u;
    __syncthreads();
    if (t < 128) sc2[t] += a;
    __syncthreads();
  }
  if (t < 128) {
    unsigned ex = sc2[t] - cD;  // exclusive prefix
    unsigned cs = cntS[t]; if (cs < 1u) cs = 1u;
    float o = rsqrtf((float)cs);
    int n = node0 + t;
    if (n < N_NODES) {
      oi[n] = o;
      row_ptr[n] = base + (int)ex;
      unsigned c = cD; if (c < 1u) c = 1u;
      float iv = rsqrtf((float)c);
      ii[n] = iv;
      coi[n] = iv * o;  // relu(ii*agg)*oi == (ii*oi)*relu(agg)
    }
    cntD[t] = ex;  // reuse as cursors
  }
  __syncthreads();
  for (int j = t; j < cnt; j += 256) {
    int pk = fit ? eL[j] : ebuf[base + j];
    unsigned dn = (unsigned)pk >> 17;
    unsigned slot = atomicAdd(&cntD[dn], 1u);
    csr_src[base + (int)slot] = pk & 0x1FFFF;
  }
}

// ---------------- GEMM1 (MFMA bf16): h1b = bf16((x*oi) @ W1), 100k x 128 x 128 ----------------

#define LPAD 136

__global__ __launch_bounds__(256) void k_gemm1(const float* __restrict__ x,
                                               const float* __restrict__ oi,
                                               const unsigned short* __restrict__ Wt1,
                                               unsigned short* __restrict__ h1b) {
  __shared__ unsigned short Xs[64 * LPAD];
  __shared__ unsigned short Ws[128 * LPAD];
  const int t = threadIdx.x;
  const int row0 = blockIdx.x * 64;
#pragma unroll
  for (int j = 0; j < 8; ++j) {
    int q = t + 256 * j;
    int n = q >> 4, c = q & 15;
    *(uint4*)(Ws + n * LPAD + c * 8) = *(const uint4*)(Wt1 + n * 128 + c * 8);
  }
#pragma unroll
  for (int j = 0; j < 4; ++j) {
    int q = t + 256 * j;
    int r = q >> 4, c = q & 15;
    int gr = row0 + r; if (gr >= N_NODES) gr = N_NODES - 1;
    const float* xp = x + (size_t)gr * 128 + c * 8;
    float4 v0 = *(const float4*)(xp);
    float4 v1 = *(const float4*)(xp + 4);
    float s = oi[gr];
    uint4 pk;
    pk.x = pack_bf16x2(v0.x * s, v0.y * s);
    pk.y = pack_bf16x2(v0.z * s, v0.w * s);
    pk.z = pack_bf16x2(v1.x * s, v1.y * s);
    pk.w = pack_bf16x2(v1.z * s, v1.w * s);
    *(uint4*)(Xs + r * LPAD + c * 8) = pk;
  }
  __syncthreads();
  const int w = t >> 6, lane = t & 63;
  const int m = lane & 15;
  const int q8 = (lane >> 4) * 8;
  f32x4 acc[8];
#pragma unroll
  for (int i = 0; i < 8; ++i) acc[i] = (f32x4){0.f, 0.f, 0.f, 0.f};
  const unsigned short* xrow = Xs + (w * 16 + m) * LPAD;
#pragma unroll
  for (int ks = 0; ks < 4; ++ks) {
    bf16x8 a = *(const bf16x8*)(xrow + ks * 32 + q8);
#pragma unroll
    for (int ct = 0; ct < 8; ++ct) {
      bf16x8 b = *(const bf16x8*)(Ws + (ct * 16 + m) * LPAD + ks * 32 + q8);
      acc[ct] = __builtin_amdgcn_mfma_f32_16x16x32_bf16(a, b, acc[ct], 0, 0, 0);
    }
  }
  const int rbase = row0 + w * 16 + (lane >> 4) * 4;
#pragma unroll
  for (int ct = 0; ct < 8; ++ct) {
    int coln = ct * 16 + m;
#pragma unroll
    for (int r = 0; r < 4; ++r) {
      int grow = rbase + r;
      if (grow < N_NODES) h1b[(size_t)grow * 128 + coln] = bf16u(acc[ct][r]);
    }
  }
}

// ---------------- AGG1+GEMM2 fused: h2b = bf16( (coi*relu(sum h1[src])) @ W2 ) -----------

__global__ __launch_bounds__(256) void k_agg1g2(const unsigned short* __restrict__ h1b,
                                                const int* __restrict__ csr_src,
                                                const int* __restrict__ row_ptr,
                                                const float* __restrict__ coi,
                                                const unsigned short* __restrict__ Wt2,
                                                unsigned short* __restrict__ h2b) {
  __shared__ unsigned short Gs[16 * LPAD];
  __shared__ unsigned short Ws[48 * LPAD];
  const int t = threadIdx.x;
  const int node0 = blockIdx.x * 16;
#pragma unroll
  for (int j = 0; j < 3; ++j) {  // W2^T 48x128 -> LDS (L2-hot)
    int q = t + 256 * j;
    int n = q >> 4, cc = q & 15;
    *(uint4*)(Ws + n * LPAD + cc * 8) = *(const uint4*)(Wt2 + n * 128 + cc * 8);
  }
  const int node = node0 + (t >> 4);
  const int c = t & 15;
  const int beg = row_ptr[node];
  const int end = row_ptr[node + 1];
  float4 a0 = make_float4(0.f, 0.f, 0.f, 0.f);
  float4 a1 = make_float4(0.f, 0.f, 0.f, 0.f);
  int j = beg;
  for (; j + 8 <= end; j += 8) {
    uint4 v[8];
#pragma unroll
    for (int i = 0; i < 8; ++i) {
      int s = csr_src[j + i];
      v[i] = *(const uint4*)(h1b + (size_t)s * 128 + 8 * c);
    }
#pragma unroll
    for (int i = 0; i < 8; ++i) {
      a0.x += bf_lo(v[i].x); a0.y += bf_hi(v[i].x);
      a0.z += bf_lo(v[i].y); a0.w += bf_hi(v[i].y);
      a1.x += bf_lo(v[i].z); a1.y += bf_hi(v[i].z);
      a1.z += bf_lo(v[i].w); a1.w += bf_hi(v[i].w);
    }
  }
  if (j + 4 <= end) {
    uint4 v[4];
#pragma unroll
    for (int i = 0; i < 4; ++i) {
      int s = csr_src[j + i];
      v[i] = *(const uint4*)(h1b + (size_t)s * 128 + 8 * c);
    }
#pragma unroll
    for (int i = 0; i < 4; ++i) {
      a0.x += bf_lo(v[i].x); a0.y += bf_hi(v[i].x);
      a0.z += bf_lo(v[i].y); a0.w += bf_hi(v[i].y);
      a1.x += bf_lo(v[i].z); a1.y += bf_hi(v[i].z);
      a1.z += bf_lo(v[i].w); a1.w += bf_hi(v[i].w);
    }
    j += 4;
  }
  for (; j < end; ++j) {
    int s = csr_src[j];
    uint4 v = *(const uint4*)(h1b + (size_t)s * 128 + 8 * c);
    a0.x += bf_lo(v.x); a0.y += bf_hi(v.x); a0.z += bf_lo(v.y); a0.w += bf_hi(v.y);
    a1.x += bf_lo(v.z); a1.y += bf_hi(v.z); a1.z += bf_lo(v.w); a1.w += bf_hi(v.w);
  }
  float sc = coi[node];
  uint4 pk;
  pk.x = pack_bf16x2(fmaxf(a0.x, 0.f) * sc, fmaxf(a0.y, 0.f) * sc);
  pk.y = pack_bf16x2(fmaxf(a0.z, 0.f) * sc, fmaxf(a0.w, 0.f) * sc);
  pk.z = pack_bf16x2(fmaxf(a1.x, 0.f) * sc, fmaxf(a1.y, 0.f) * sc);
  pk.w = pack_bf16x2(fmaxf(a1.z, 0.f) * sc, fmaxf(a1.w, 0.f) * sc);
  *(uint4*)(Gs + (t >> 4) * LPAD + 8 * c) = pk;
  __syncthreads();
  // GEMM2: 16x128 @ (48x128)^T -> 16x48 ; wave w = col-tile w (0..2), wave 3 idle
  const int w = t >> 6, lane = t & 63;
  if (w < 3) {
    const int m = lane & 15;
    const int q8 = (lane >> 4) * 8;
    f32x4 acc = (f32x4){0.f, 0.f, 0.f, 0.f};
    const unsigned short* grow_p = Gs + m * LPAD;
#pragma unroll
    for (int ks = 0; ks < 4; ++ks) {
      bf16x8 a = *(const bf16x8*)(grow_p + ks * 32 + q8);
      bf16x8 b = *(const bf16x8*)(Ws + (w * 16 + m) * LPAD + ks * 32 + q8);
      acc = __builtin_amdgcn_mfma_f32_16x16x32_bf16(a, b, acc, 0, 0, 0);
    }
    int coln = w * 16 + m;
    if (coln < 40) {
      const int rbase = (lane >> 4) * 4;
#pragma unroll
      for (int r = 0; r < 4; ++r)
        h2b[(size_t)(node0 + rbase + r) * 64 + coln] = bf16u(acc[r]);
    }
  }
}

// ---------------- AGG2: out = ii * sum h2[src]  (8 lanes/node, uint4; lanes 0-4 active) ----

__global__ __launch_bounds__(256) void k_agg2(const unsigned short* __restrict__ h2b,
                                              const int* __restrict__ csr_src,
                                              const int* __restrict__ row_ptr,
                                              const float* __restrict__ ii,
                                              float* __restrict__ out) {
  const int t = threadIdx.x;
  const int node = blockIdx.x * 32 + (t >> 3);
  const int c = t & 7;
  if (c >= 5) return;  // 40 ch = 5 lanes x 8 ch
  const int beg = row_ptr[node];
  const int end = row_ptr[node + 1];
  float a0 = 0.f, a1 = 0.f, a2 = 0.f, a3 = 0.f, a4 = 0.f, a5 = 0.f, a6 = 0.f, a7 = 0.f;
  int j = beg;
  for (; j + 8 <= end; j += 8) {
    uint4 v[8];
#pragma unroll
    for (int i = 0; i < 8; ++i) {
      int s = csr_src[j + i];
      v[i] = *(const uint4*)(h2b + (size_t)s * 64 + 8 * c);
    }
#pragma unroll
    for (int i = 0; i < 8; ++i) {
      a0 += bf_lo(v[i].x); a1 += bf_hi(v[i].x);
      a2 += bf_lo(v[i].y); a3 += bf_hi(v[i].y);
      a4 += bf_lo(v[i].z); a5 += bf_hi(v[i].z);
      a6 += bf_lo(v[i].w); a7 += bf_hi(v[i].w);
    }
  }
  if (j + 4 <= end) {
    uint4 v[4];
#pragma unroll
    for (int i = 0; i < 4; ++i) {
      int s = csr_src[j + i];
      v[i] = *(const uint4*)(h2b + (size_t)s * 64 + 8 * c);
    }
#pragma unroll
    for (int i = 0; i < 4; ++i) {
      a0 += bf_lo(v[i].x); a1 += bf_hi(v[i].x);
      a2 += bf_lo(v[i].y); a3 += bf_hi(v[i].y);
      a4 += bf_lo(v[i].z); a5 += bf_hi(v[i].z);
      a6 += bf_lo(v[i].w); a7 += bf_hi(v[i].w);
    }
    j += 4;
  }
  for (; j < end; ++j) {
    int s = csr_src[j];
    uint4 v = *(const uint4*)(h2b + (size_t)s * 64 + 8 * c);
    a0 += bf_lo(v.x); a1 += bf_hi(v.x);
    a2 += bf_lo(v.y); a3 += bf_hi(v.y);
    a4 += bf_lo(v.z); a5 += bf_hi(v.z);
    a6 += bf_lo(v.w); a7 += bf_hi(v.w);
  }
  float sc = ii[node];
  float4 o0 = make_float4(a0 * sc, a1 * sc, a2 * sc, a3 * sc);
  float4 o1 = make_float4(a4 * sc, a5 * sc, a6 * sc, a7 * sc);
  float* op = out + (size_t)node * 40 + 8 * c;
  *(float4*)(op) = o0;
  *(float4*)(op + 4) = o1;
}

// ---------------- launch ----------------

extern "C" void kernel_launch(void* const* d_in, const int* in_sizes, int n_in,
                              void* d_out, int out_size, void* d_ws, size_t ws_size,
                              hipStream_t stream) {
  const float* x  = (const float*)d_in[0];
  const int* ei   = (const int*)d_in[1];
  const float* W1 = (const float*)d_in[2];
  const float* W2 = (const float*)d_in[3];
  const int* src = ei;
  const int* dst = ei + N_EDGES;
  float* out = (float*)d_out;

  char* p = (char*)d_ws;
  auto alloc = [&](size_t b) -> void* {
    char* r = p;
    p += (b + 255) & ~(size_t)255;
    return (void*)r;
  };
  float* oi             = (float*)alloc((size_t)N_NODES * 4);
  float* ii             = (float*)alloc((size_t)N_NODES * 4);
  float* coi            = (float*)alloc((size_t)N_NODES * 4);
  int* row_ptr          = (int*)alloc((size_t)(N_NODES + 1) * 4);
  unsigned* histGd      = (unsigned*)alloc((size_t)NBUCK * NCHUNK * 4);
  unsigned* histGs      = (unsigned*)alloc((size_t)NBUCK * NCHUNK * 4);
  unsigned* btot        = (unsigned*)alloc((size_t)2 * NBUCK * 4);
  int* bbase            = (int*)alloc((size_t)(NBUCK + 1) * 4);
  int* sbase            = (int*)alloc((size_t)(NBUCK + 1) * 4);
  int* ebuf             = (int*)alloc((size_t)N_EDGES * 4);
  unsigned char* ebuf2  = (unsigned char*)alloc((size_t)N_EDGES);
  int* csr_src          = (int*)alloc((size_t)N_EDGES * 4);
  unsigned short* Wt1   = (unsigned short*)alloc((size_t)128 * 128 * 2);
  unsigned short* Wt2   = (unsigned short*)alloc((size_t)48 * 128 * 2);
  unsigned short* h1b   = (unsigned short*)alloc((size_t)N_NODES * 128 * 2);
  unsigned short* h2b   = (unsigned short*)alloc((size_t)N_NODES * 64 * 2);

  k_hist<<<NCHUNK, 256, 0, stream>>>(src, dst, histGd, histGs, W1, W2, Wt1, Wt2);
  k_offs<<<2 * NBUCK, 256, 0, stream>>>(histGd, histGs, btot);
  k_bscan2<<<2, 1024, 0, stream>>>(btot, bbase, sbase, row_ptr);
  k_part<<<NCHUNK, 256, 0, stream>>>(src, dst, histGd, histGs, bbase, sbase, ebuf, ebuf2);
  k_buckets<<<NBUCK, 256, 0, stream>>>(ebuf, ebuf2, bbase, sbase, oi, row_ptr, csr_src,
                                       ii, coi);
  k_gemm1<<<(N_NODES + 63) / 64, 256, 0, stream>>>(x, oi, Wt1, h1b);
  k_agg1g2<<<N_NODES / 16, 256, 0, stream>>>(h1b, csr_src, row_ptr, coi, Wt2, h2b);
  k_agg2<<<N_NODES / 32, 256, 0, stream>>>(h2b, csr_src, row_ptr, ii, out);
}